// Round 9
// baseline (111.028 us; speedup 1.0000x reference)
//
#include <hip/hip_runtime.h>

#define SEQ_N 1024
#define BATCH 64
#define NW    8            // waves per block -> 2 waves per SIMD (latency hiding)
#define RPL   2            // rows per lane: 8 waves * 64 lanes * 2 = 1024 rows
#define KSL   16           // epoch length == inter-wave slack - 1
#define DELTA (64 + KSL)   // column delay between consecutive waves (80)
#define RINGN 80           // 64-slot ring + 16 mirror slots (wrap-free reads)
#define PAD_F 640          // front pad: max off = 7*80+63 = 623
#define PAD_B 672          // back pad: max y prefetch index = 103*16+31 = 1679

// Wave-wide shift-up-by-1 in one instruction (DPP wave_shr:1, ctrl 0x138).
// bound_ctrl=false -> lane 0 takes `fill` (INF) = top-row boundary for free.
__device__ __forceinline__ float wave_shr1(float v, float fill) {
    return __int_as_float(__builtin_amdgcn_update_dpp(
        __float_as_int(fill), __float_as_int(v), 0x138, 0xF, 0xF, false));
}

// 8 waves cooperate on one DTW matrix. Wave w owns rows [w*128, w*128+128),
// lane l owns rows w*128 + 2l, +1. Lane (w,l) at step s computes column
// j = s - w*DELTA - l. In-wave dep: DPP. Cross-wave dep: LDS ring, slot =
// producer step & 63, slack 17 steps, one barrier per 16-step epoch
// (identical machinery to the verified 4-wave version).
// Corner seed: D[0,0] needs up=0 at (epoch 0, k2=0, tid 0); diag_top is then
// restored to INF so cell (0,1) doesn't inherit 0 through the diag path.
__global__ __launch_bounds__(NW * 64, 1) void dtw_kernel(const float* __restrict__ x,
                                                         const float* __restrict__ y,
                                                         float* __restrict__ dists) {
    __shared__ float sy_raw[PAD_F + SEQ_N + PAD_B];
    __shared__ float ring[NW - 1][RINGN];

    const int b   = blockIdx.x;
    const int tid = threadIdx.x;
    const int w   = tid >> 6;        // wave id 0..7
    const int l   = tid & 63;        // lane id
    const float INF = 3.0e37f;
    const int  off = w * DELTA + l;  // column delay of this lane
    const bool is_ring_l0 = (l == 0) && (w > 0);
    const bool is_tid0 = (tid == 0);

    // zero pads
    for (int i = tid; i < PAD_F; i += NW * 64) sy_raw[i] = 0.0f;
    for (int i = tid; i < PAD_B; i += NW * 64) sy_raw[PAD_F + SEQ_N + i] = 0.0f;
    // stage y (float4 per thread, first 256 threads)
    if (tid < SEQ_N / 4)
        ((float4*)(sy_raw + PAD_F))[tid] = ((const float4*)(y + b * SEQ_N))[tid];
    // this lane's 2 x-rows (one float2, coalesced)
    const float2 xv = *((const float2*)(x + b * SEQ_N + w * (64 * RPL) + l * RPL));
    const float xr0 = xv.x, xr1 = xv.y;
    __syncthreads();

    const float* const yp = sy_raw + PAD_F - off;   // yp[s] == y[s - off]

    float c0 = INF, c1 = INF;        // col[0..1]
    float diag_top = INF, bottom = INF;
    float yA[KSL], yB[KSL], rb[KSL], bt[KSL];

    // prologue: y values for epoch 0
    #pragma unroll
    for (int k = 0; k < KSL; ++k) yA[k] = yp[k];

// One 16-step epoch. YU = y values for this epoch, YF = buffer filled with
// next epoch's y. Ring values for the whole epoch are read right after the
// barrier; bottoms are collected in bt[] and written at epoch end.
#define EPOCH(MASKED, FIRST, S0, YU, YF)                                     \
  {                                                                          \
    __syncthreads();                                                         \
    if (w > 0) {                                                             \
      int rbase = ((S0) & 63) + 47; if (rbase >= 64) rbase -= 64;            \
      const float* rp = ring[w - 1] + rbase;                                 \
      _Pragma("unroll")                                                      \
      for (int k2 = 0; k2 < KSL; ++k2) rb[k2] = rp[k2];                      \
    } else {                                                                 \
      _Pragma("unroll")                                                      \
      for (int k2 = 0; k2 < KSL; ++k2) rb[k2] = INF;                         \
    }                                                                        \
    _Pragma("unroll")                                                        \
    for (int k2 = 0; k2 < KSL; ++k2) YF[k2] = yp[(S0) + KSL + k2];           \
    _Pragma("unroll")                                                        \
    for (int k2 = 0; k2 < KSL; ++k2) {                                       \
      const float up_dpp = wave_shr1(bottom, INF);                           \
      float upv = is_ring_l0 ? rb[k2] : up_dpp;                              \
      if ((FIRST) && k2 == 0 && is_tid0) upv = 0.0f;  /* seed D[0,0]=d */    \
      const float yj = YU[k2];                                               \
      bool act = true;                                                       \
      if (MASKED) act = ((unsigned)((S0) + k2 - off) < (unsigned)SEQ_N);     \
      if (act) {                                                             \
        const float d0 = xr0 - yj, d1 = xr1 - yj;                            \
        const float t0 = diag_top + fabsf(d0);                               \
        const float t1 = c0 + fabsf(d1);                                     \
        float v = upv;                                                       \
        v = fminf(fminf(t0, c0), v) + fabsf(d0); c0 = v;                     \
        v = fminf(fminf(t1, c1), v) + fabsf(d1); c1 = v;                     \
        diag_top = upv; bottom = v;                                          \
      }                                                                      \
      if ((FIRST) && k2 == 0 && is_tid0) diag_top = INF; /* un-contaminate */\
      bt[k2] = bottom;                                                       \
    }                                                                        \
    if (w < NW - 1 && l == 63) {                                             \
      const int mm = (S0) & 63;                                              \
      float* wp = ring[w] + mm;                                              \
      _Pragma("unroll")                                                      \
      for (int k2 = 0; k2 < KSL; ++k2) wp[k2] = bt[k2];                      \
      if (mm == 0) {                                                         \
        _Pragma("unroll")                                                    \
        for (int k2 = 0; k2 < KSL; ++k2) ring[w][64 + k2] = bt[k2];          \
      }                                                                      \
    }                                                                        \
  }

    // epoch 0 (with corner seed) + epoch 1
    EPOCH(true, true, 0, yA, yB);
    EPOCH(true, false, 16, yB, yA);
    int s0 = 32;
    // epochs 2..39: ramp-up (max off = 623, covered by epoch 38)
    for (int it = 0; it < 19; ++it) {
        EPOCH(true, false, s0, yA, yB);
        EPOCH(true, false, s0 + 16, yB, yA);
        s0 += 32;
    }
    // epochs 40..63: steady (s0 = 640..1008; all lanes active on [623,1023])
    for (int it = 0; it < 12; ++it) {
        EPOCH(false, false, s0, yA, yB);
        EPOCH(false, false, s0 + 16, yB, yA);
        s0 += 32;
    }
    // epochs 64..103: ramp-down (last active step = 1023 + 623 = 1646)
    for (int it = 0; it < 20; ++it) {
        EPOCH(true, false, s0, yA, yB);
        EPOCH(true, false, s0 + 16, yB, yA);
        s0 += 32;
    }
#undef EPOCH

    // D[1023,1023] lives in wave 7 lane 63's c1
    if (tid == NW * 64 - 1) dists[b] = c1 * (1.0f / (2.0f * (float)SEQ_N));
}

// Mean over the 64 per-batch distances -> single float output.
__global__ void dtw_reduce_kernel(const float* __restrict__ dists,
                                  float* __restrict__ out) {
    float v = dists[threadIdx.x] * (1.0f / (float)BATCH);
    #pragma unroll
    for (int o = 32; o > 0; o >>= 1) v += __shfl_down(v, o);
    if (threadIdx.x == 0) out[0] = v;
}

extern "C" void kernel_launch(void* const* d_in, const int* in_sizes, int n_in,
                              void* d_out, int out_size, void* d_ws, size_t ws_size,
                              hipStream_t stream) {
    const float* x = (const float*)d_in[0];
    const float* y = (const float*)d_in[1];
    float* out = (float*)d_out;
    float* dists = (float*)d_ws;  // 64 floats of scratch

    dtw_kernel<<<BATCH, NW * 64, 0, stream>>>(x, y, dists);
    dtw_reduce_kernel<<<1, BATCH, 0, stream>>>(dists, out);
}

// Round 10
// 102.641 us; speedup vs baseline: 1.0817x; 1.0817x over previous
//
#include <hip/hip_runtime.h>

#define SEQ_N 1024
#define BATCH 64
#define NW    4            // waves per block (per batch element)
#define RPL   4            // rows per lane: 4 waves * 64 lanes * 4 = 1024 rows
#define KSL   16           // epoch length == inter-wave slack - 1
#define DELTA (64 + KSL)   // column delay between consecutive waves (80)
#define RINGN 80           // 64-slot ring + 16 mirror slots (wrap-free reads)
#define PAD_F 304          // front pad: max off = 3*80+63 = 303
#define PAD_B 352          // back pad: last y prefetch index = 1359

// Wave-wide shift-up-by-1 in one instruction (DPP wave_shr:1, ctrl 0x138).
// bound_ctrl=false -> lane 0 takes `fill` (INF) = top-row boundary for free.
__device__ __forceinline__ float wave_shr1(float v, float fill) {
    return __int_as_float(__builtin_amdgcn_update_dpp(
        __float_as_int(fill), __float_as_int(v), 0x138, 0xF, 0xF, false));
}

// 4 waves per DTW matrix, NO epoch barriers: pairwise producer/consumer
// pipeline through LDS epoch-counter flags. Wave w owns rows [w*256,+256),
// lane l owns rows w*256+4l..+4. Lane (w,l) at step s computes col j=s-off.
//
// Ring protocol (per ring r, producer wave r, consumer wave r+1):
//   prodf[r] = #epochs whose ring data is fully written (flag stored after
//              ds_writes + s_waitcnt lgkmcnt(0) -> data visible first).
//   consf[r] = #epochs whose ring data the consumer has finished reading.
//   consumer epoch E reads producer steps 16E-17..16E-2 -> needs prodf >= E.
//   producer epoch E overwrites slots read by consumer epochs {E-3,E-2}
//     (slots recycle every 64 steps = 4 epochs) -> needs consf >= E-1.
// Deadlock-free: single block => all waves co-resident; bounded-ring waits.
//
// Corner seed: D[0,0] needs up=0 at (epoch 0, k2=0, tid 0); diag_top is then
// restored to INF so cell (0,1) doesn't inherit 0 through the diag path.
__global__ __launch_bounds__(256, 1) void dtw_kernel(const float* __restrict__ x,
                                                     const float* __restrict__ y,
                                                     float* __restrict__ dists) {
    __shared__ float sy_raw[PAD_F + SEQ_N + PAD_B];
    __shared__ float ring[NW - 1][RINGN];
    __shared__ int prodf[NW - 1];
    __shared__ int consf[NW - 1];

    const int b   = blockIdx.x;
    const int tid = threadIdx.x;
    const int w   = tid >> 6;        // wave id 0..3
    const int l   = tid & 63;        // lane id
    const float INF = 3.0e37f;
    const int  off = w * DELTA + l;  // column delay of this lane
    const bool is_ring_l0 = (l == 0) && (w > 0);
    const bool is_tid0 = (tid == 0);

    if (tid < NW - 1) { prodf[tid] = 0; consf[tid] = 0; }
    // zero pads
    for (int i = tid; i < PAD_F; i += 256) sy_raw[i] = 0.0f;
    for (int i = tid; i < PAD_B; i += 256) sy_raw[PAD_F + SEQ_N + i] = 0.0f;
    // stage y (one float4 per thread)
    ((float4*)(sy_raw + PAD_F))[tid] = ((const float4*)(y + b * SEQ_N))[tid];
    // this lane's 4 x-rows (one float4)
    const float4 xv = *((const float4*)(x + b * SEQ_N + w * 256 + l * RPL));
    const float xr0 = xv.x, xr1 = xv.y, xr2 = xv.z, xr3 = xv.w;
    __syncthreads();   // the ONLY block-wide barrier

    const float* const yp = sy_raw + PAD_F - off;   // yp[s] == y[s - off]

    float c0 = INF, c1 = INF, c2 = INF, c3 = INF;   // col[0..3]
    float diag_top = INF, bottom = INF;
    float yA[KSL], yB[KSL], rb[KSL], bt[KSL];

    // prologue: y values for epoch 0
    #pragma unroll
    for (int k = 0; k < KSL; ++k) yA[k] = yp[k];

// One 16-step epoch, barrier-free. YU = y regs for this epoch, YF = filled
// with next epoch's y. Ring read at epoch head (after prod-flag wait);
// bottoms collected in bt[] and published at epoch end (before prod-flag).
#define EPOCH(MASKED, FIRST, S0, YU, YF)                                     \
  {                                                                          \
    const int e_ = (S0) >> 4;                                                \
    if (w > 0) {                                                             \
      volatile const int* pf = prodf + (w - 1);                              \
      while (*pf < e_) { }                                                   \
      __builtin_amdgcn_sched_barrier(0);  /* no hoisting rb above spin */    \
      int rbase = ((S0) & 63) + 47; if (rbase >= 64) rbase -= 64;            \
      const float* rp = ring[w - 1] + rbase;                                 \
      _Pragma("unroll")                                                      \
      for (int k2 = 0; k2 < KSL; ++k2) rb[k2] = rp[k2];                      \
    } else {                                                                 \
      _Pragma("unroll")                                                      \
      for (int k2 = 0; k2 < KSL; ++k2) rb[k2] = INF;                         \
    }                                                                        \
    _Pragma("unroll")                                                        \
    for (int k2 = 0; k2 < KSL; ++k2) YF[k2] = yp[(S0) + KSL + k2];           \
    _Pragma("unroll")                                                        \
    for (int k2 = 0; k2 < KSL; ++k2) {                                       \
      const float up_dpp = wave_shr1(bottom, INF);                           \
      float upv = is_ring_l0 ? rb[k2] : up_dpp;                              \
      if ((FIRST) && k2 == 0 && is_tid0) upv = 0.0f;  /* seed D[0,0]=d */    \
      const float yj = YU[k2];                                               \
      bool act = true;                                                       \
      if (MASKED) act = ((unsigned)((S0) + k2 - off) < (unsigned)SEQ_N);     \
      if (act) {                                                             \
        const float d0 = xr0 - yj, d1 = xr1 - yj,                            \
                    d2 = xr2 - yj, d3 = xr3 - yj;                            \
        const float t0 = diag_top + fabsf(d0);                               \
        const float t1 = c0 + fabsf(d1);                                     \
        const float t2 = c1 + fabsf(d2);                                     \
        const float t3 = c2 + fabsf(d3);                                     \
        float v = upv;                                                       \
        v = fminf(fminf(t0, c0), v) + fabsf(d0); c0 = v;                     \
        v = fminf(fminf(t1, c1), v) + fabsf(d1); c1 = v;                     \
        v = fminf(fminf(t2, c2), v) + fabsf(d2); c2 = v;                     \
        v = fminf(fminf(t3, c3), v) + fabsf(d3); c3 = v;                     \
        diag_top = upv; bottom = v;                                          \
      }                                                                      \
      if ((FIRST) && k2 == 0 && is_tid0) diag_top = INF; /* un-contaminate */\
      bt[k2] = bottom;                                                       \
    }                                                                        \
    if (w > 0 && l == 0) {                                                   \
      __builtin_amdgcn_sched_barrier(0);  /* rb fully consumed above */      \
      *(volatile int*)(consf + (w - 1)) = e_ + 1;                            \
    }                                                                        \
    if (w < NW - 1) {                                                        \
      volatile const int* cf = consf + w;                                    \
      while (*cf < e_ - 1) { }          /* WAR: slots recycle in 4 epochs */ \
      __builtin_amdgcn_sched_barrier(0);                                     \
      if (l == 63) {                                                         \
        const int mm = (S0) & 63;                                            \
        float* wp = ring[w] + mm;                                            \
        _Pragma("unroll")                                                    \
        for (int k2 = 0; k2 < KSL; ++k2) wp[k2] = bt[k2];                    \
        if (mm == 0) {                                                       \
          _Pragma("unroll")                                                  \
          for (int k2 = 0; k2 < KSL; ++k2) ring[w][64 + k2] = bt[k2];        \
        }                                                                    \
        asm volatile("s_waitcnt lgkmcnt(0)" ::: "memory");                   \
        __builtin_amdgcn_sched_barrier(0);                                   \
        *(volatile int*)(prodf + w) = e_ + 1;                                \
      }                                                                      \
    }                                                                        \
  }

    // epoch 0 (with corner seed) + epoch 1
    EPOCH(true, true, 0, yA, yB);
    EPOCH(true, false, 16, yB, yA);
    int s0 = 32;
    // epochs 2..19: ramp-up (some lanes inactive)
    for (int it = 1; it < 10; ++it) {
        EPOCH(true, false, s0, yA, yB);
        EPOCH(true, false, s0 + 16, yB, yA);
        s0 += 32;
    }
    // epochs 20..63: steady, all 1024 lanes interior (steps 320..1023)
    for (int it = 0; it < 22; ++it) {
        EPOCH(false, false, s0, yA, yB);
        EPOCH(false, false, s0 + 16, yB, yA);
        s0 += 32;
    }
    // epochs 64..83: ramp-down (steps 1024..1343; last active step is 1326)
    for (int it = 0; it < 10; ++it) {
        EPOCH(true, false, s0, yA, yB);
        EPOCH(true, false, s0 + 16, yB, yA);
        s0 += 32;
    }
#undef EPOCH

    // D[1023,1023] lives in wave 3 lane 63's c3
    if (tid == 255) dists[b] = c3 * (1.0f / (2.0f * (float)SEQ_N));
}

// Mean over the 64 per-batch distances -> single float output.
__global__ void dtw_reduce_kernel(const float* __restrict__ dists,
                                  float* __restrict__ out) {
    float v = dists[threadIdx.x] * (1.0f / (float)BATCH);
    #pragma unroll
    for (int o = 32; o > 0; o >>= 1) v += __shfl_down(v, o);
    if (threadIdx.x == 0) out[0] = v;
}

extern "C" void kernel_launch(void* const* d_in, const int* in_sizes, int n_in,
                              void* d_out, int out_size, void* d_ws, size_t ws_size,
                              hipStream_t stream) {
    const float* x = (const float*)d_in[0];
    const float* y = (const float*)d_in[1];
    float* out = (float*)d_out;
    float* dists = (float*)d_ws;  // 64 floats of scratch

    dtw_kernel<<<BATCH, 256, 0, stream>>>(x, y, dists);
    dtw_reduce_kernel<<<1, BATCH, 0, stream>>>(dists, out);
}